// Round 2
// baseline (137.822 us; speedup 1.0000x reference)
//
#include <hip/hip_runtime.h>
#include <hip/hip_fp16.h>

#define N_DET 128
#define N_T   2048
#define NPIX  65536   // 256*256
#define NBATCH 4
#define CHUNK 8               // dets per block
#define NCHUNK (N_DET / CHUNK)  // 16
#define G 2                   // det rows per LDS buffer
#define NGRP (CHUNK / G)      // 4 group-iters per block
#define PT 1024               // pixels per block == threads per block

typedef float f4_t __attribute__((ext_vector_type(4)));

// Kernel 1: transpose+pack sino (B, N_DET, N_T) fp32 -> ws (N_DET, N_T) of
// 8-byte records { s_t[b0..b3] } as 4 fp16. ws = 2 MB (L2-resident).
// Also zeroes out[] (N_DET*N_T == NBATCH*NPIX == 262144 floats).
__global__ __launch_bounds__(256) void sino_pack_kernel(
    const float* __restrict__ sino, float2* __restrict__ ws,
    float* __restrict__ out) {
  const int idx = blockIdx.x * blockDim.x + threadIdx.x;  // idx = d*N_T + t
  const __half2 lo = __floats2half2_rn(
      __builtin_nontemporal_load(sino + 0 * N_DET * N_T + idx),
      __builtin_nontemporal_load(sino + 1 * N_DET * N_T + idx));
  const __half2 hi = __floats2half2_rn(
      __builtin_nontemporal_load(sino + 2 * N_DET * N_T + idx),
      __builtin_nontemporal_load(sino + 3 * N_DET * N_T + idx));
  union { struct { __half2 a, b; } h; float2 f; } u;
  u.h.a = lo;
  u.h.b = hi;
  ws[idx] = u.f;
  out[idx] = 0.0f;  // exact cover: 128*2048 == 4*65536
}

// Kernel 2: block = (1024-pixel tile) x (8-det chunk). Loops over 4 groups of
// 2 det rows with double-buffered 2x32 KB LDS:
//   - 64 KB LDS/block -> 2 blocks/CU -> 8 waves/SIMD (vs 31% occupancy before)
//   - per-thread 64 B lut line (all 8 dets) loaded ONCE up-front: 4 b128 in
//     flight (round-0-style MLP, which round 1 lost when VGPR fell 132->52)
//   - T14 split staging: issue next group's loads BEFORE compute, ds_write
//     AFTER, one barrier per group-iter -> stage latency hides under compute.
// Partials accumulate in registers across the 4 groups; 4 atomics per thread.
__global__ __launch_bounds__(1024, 8) void das_lds_kernel(
    const float* __restrict__ lut, const float2* __restrict__ ws,
    float* __restrict__ out) {
  __shared__ float2 sino_s[2][G * N_T];  // 2 x 32 KB

  const int tid = threadIdx.x;
  const int tile = blockIdx.x;  // 0..63
  const int c = blockIdx.y;     // det chunk 0..15
  const int p = tile * PT + tid;

  // One contiguous 64 B lut line per thread: 8 dets x (tof, alpha).
  f4_t l[4];
  {
    const f4_t* lp =
        reinterpret_cast<const f4_t*>(lut + ((size_t)p * N_DET + c * CHUNK) * 2);
#pragma unroll
    for (int j = 0; j < 4; ++j) l[j] = lp[j];
  }

  // Stage group 0 into buffer 0 (2 rows x 2048 float2 = 2048 float4).
  const float4* wsrc = reinterpret_cast<const float4*>(ws + (size_t)c * CHUNK * N_T);
  {
    const float4 s0 = wsrc[tid];
    const float4 s1 = wsrc[tid + 1024];
    float4* dst = reinterpret_cast<float4*>(&sino_s[0][0]);
    dst[tid] = s0;
    dst[tid + 1024] = s1;
  }
  __syncthreads();

  float a0 = 0.f, a1 = 0.f, a2 = 0.f, a3 = 0.f;

#pragma unroll
  for (int grp = 0; grp < NGRP; ++grp) {
    const int cur = grp & 1;

    // T14: issue next group's stage loads before compute (L2 latency hides
    // under the LDS-gather compute below).
    float4 n0, n1;
    if (grp < NGRP - 1) {
      n0 = wsrc[(grp + 1) * 2048 + tid];
      n1 = wsrc[(grp + 1) * 2048 + tid + 1024];
    }

    // Compute dets d = c*8 + grp*2 + {0,1} from LDS buffer `cur`.
    const float2* sbuf = &sino_s[cur][0];
#pragma unroll
    for (int r = 0; r < G; ++r) {
      const int d = c * CHUNK + grp * G + r;
      const float tof = r ? l[grp].z : l[grp].x;
      const float al  = r ? l[grp].w : l[grp].y;
      const float kf = floorf(tof);
      const bool valid = (kf >= 0.0f) && (kf < (float)(N_T - 1));
      const float kcl = fminf(fmaxf(kf, 0.0f), (float)(N_T - 2));
      const int k0 = (int)kcl;
      const float apd = 0.5f - 0.5f * cosf(6.28318530717958647692f *
                                           ((float)d / (float)(N_DET - 1)));
      const float w = valid ? apd : 0.0f;

      const float2 r0 = sbuf[r * N_T + k0];      // ds_read_b64: tap t
      const float2 r1 = sbuf[r * N_T + k0 + 1];  // ds_read_b64: tap t+1
      const __half2* h0 = reinterpret_cast<const __half2*>(&r0);
      const __half2* h1 = reinterpret_cast<const __half2*>(&r1);
      const float2 s0a = __half22float2(h0[0]);  // t:   b0,b1
      const float2 s0b = __half22float2(h0[1]);  // t:   b2,b3
      const float2 s1a = __half22float2(h1[0]);  // t+1: b0,b1
      const float2 s1b = __half22float2(h1[1]);  // t+1: b2,b3

      a0 += w * (s0a.x + al * (s1a.x - s0a.x));
      a1 += w * (s0a.y + al * (s1a.y - s0a.y));
      a2 += w * (s0b.x + al * (s1b.x - s0b.x));
      a3 += w * (s0b.y + al * (s1b.y - s0b.y));
    }

    // Write next group's data into the other buffer. The barrier at the end
    // of the PREVIOUS iter guarantees everyone is done reading it.
    if (grp < NGRP - 1) {
      float4* dst = reinterpret_cast<float4*>(&sino_s[cur ^ 1][0]);
      dst[tid] = n0;
      dst[tid + 1024] = n1;
    }
    __syncthreads();
  }

  const float nrm = 1.0f / 63.5f;  // sum(apod) == 63.5 analytically
  atomicAdd(out + 0 * NPIX + p, a0 * nrm);
  atomicAdd(out + 1 * NPIX + p, a1 * nrm);
  atomicAdd(out + 2 * NPIX + p, a2 * nrm);
  atomicAdd(out + 3 * NPIX + p, a3 * nrm);
}

// Fallback (no workspace): direct fp32 gather from original layout.
__global__ __launch_bounds__(256) void das_fallback_kernel(
    const float* __restrict__ lut, const float* __restrict__ S,
    float* __restrict__ out) {
  const int lane = threadIdx.x & 63;
  const int p = blockIdx.x * 4 + (threadIdx.x >> 6);

  const float4 lv =
      reinterpret_cast<const float4*>(lut + (size_t)p * 2 * N_DET)[lane];

  float acc0 = 0.f, acc1 = 0.f, acc2 = 0.f, acc3 = 0.f;
  float wsum = 0.f;

#pragma unroll
  for (int j = 0; j < 2; ++j) {
    const int d = 2 * lane + j;
    const float tof = j ? lv.z : lv.x;
    const float a   = j ? lv.w : lv.y;
    const float kf = floorf(tof);
    const bool valid = (kf >= 0.0f) && (kf < (float)(N_T - 1));
    const float kcl = fminf(fmaxf(kf, 0.0f), (float)(N_T - 2));
    const int k0 = (int)kcl;
    const float apd =
        0.5f - 0.5f * cosf(6.28318530717958647692f *
                           (1.0f / (float)(N_DET - 1)) * (float)d);
    wsum += apd;
    const float w = valid ? apd : 0.0f;
    const float om = 1.0f - a;
    const float* row = S + (size_t)d * N_T + k0;
    acc0 += w * (om * row[0 * N_DET * N_T] + a * row[0 * N_DET * N_T + 1]);
    acc1 += w * (om * row[1 * N_DET * N_T] + a * row[1 * N_DET * N_T + 1]);
    acc2 += w * (om * row[2 * N_DET * N_T] + a * row[2 * N_DET * N_T + 1]);
    acc3 += w * (om * row[3 * N_DET * N_T] + a * row[3 * N_DET * N_T + 1]);
  }

#pragma unroll
  for (int off = 32; off > 0; off >>= 1) {
    acc0 += __shfl_xor(acc0, off);
    acc1 += __shfl_xor(acc1, off);
    acc2 += __shfl_xor(acc2, off);
    acc3 += __shfl_xor(acc3, off);
    wsum += __shfl_xor(wsum, off);
  }

  if (lane == 0) {
    const float inv = 1.0f / fmaxf(wsum, 1.17549435e-38f);
    out[0 * NPIX + p] = acc0 * inv;
    out[1 * NPIX + p] = acc1 * inv;
    out[2 * NPIX + p] = acc2 * inv;
    out[3 * NPIX + p] = acc3 * inv;
  }
}

extern "C" void kernel_launch(void* const* d_in, const int* in_sizes, int n_in,
                              void* d_out, int out_size, void* d_ws, size_t ws_size,
                              hipStream_t stream) {
  const float* sino = (const float*)d_in[0];  // (B,1,N_DET,N_T) fp32
  const float* lut  = (const float*)d_in[1];  // (NY,NX,N_DET,2) fp32
  float* out = (float*)d_out;                 // (B,1,NY,NX) fp32

  const size_t need = (size_t)N_DET * N_T * 8;  // 2 MB packed ws
  if (ws_size >= need) {
    float2* ws = (float2*)d_ws;
    sino_pack_kernel<<<(N_DET * N_T) / 256, 256, 0, stream>>>(sino, ws, out);
    dim3 grid(NPIX / PT, NCHUNK);
    das_lds_kernel<<<grid, 1024, 0, stream>>>(lut, ws, out);
  } else {
    das_fallback_kernel<<<NPIX / 4, 256, 0, stream>>>(lut, sino, out);
  }
}